// Round 6
// baseline (576.982 us; speedup 1.0000x reference)
//
#include <hip/hip_runtime.h>
#include <math.h>

#define N_PTS     131072
#define G_NUMS    30
#define G_SIZE    100
#define PT_STRIDE (N_PTS / G_NUMS)   // 4369
#define TPB       512
#define NWAVES    (TPB / 64)
#define BINS      4096
#define SHIFT     20
#define SAMPLE_GRPS 1024             // first 4096 points as iid sample
#define RANK_CUT  24                 // 24th-smallest sample -> tau (P(miss) ~ 1e-15)
#define CAP       2048               // survivor cap per (b,g); E~768
#define TIE_CAP   64
#define TILE      2048               // points per filter block
#define DONE_IDX  250                // done-counter slot in counts[] (NG=240 < 250)

__device__ __forceinline__ float dist2f(float px, float py, float pz,
                                        float qx, float qy, float qz) {
    float dx = px - qx, dy = py - qy, dz = pz - qz;
    return fmaf(dx, dx, fmaf(dy, dy, dz * dz));
}

// Smallest bin T with cumulative count >= rank. s_hist populated+synced on entry.
__device__ __forceinline__ unsigned find_bin(unsigned* s_hist, unsigned* s_wsum,
                                             unsigned* s_T, unsigned rank,
                                             int tid, int lane, int wid) {
    unsigned hv[8], csum = 0;
#pragma unroll
    for (int j = 0; j < 8; j++) { hv[j] = s_hist[tid * 8 + j]; csum += hv[j]; }
    unsigned inc = csum;
#pragma unroll
    for (int off = 1; off < 64; off <<= 1) {
        unsigned n = __shfl_up(inc, off);
        if (lane >= off) inc += n;
    }
    __syncthreads();
    if (lane == 63) s_wsum[wid] = inc;
    __syncthreads();
    unsigned base = 0;
    for (int w = 0; w < wid; w++) base += s_wsum[w];
    unsigned c = base + inc - csum;
#pragma unroll
    for (int j = 0; j < 8; j++) {
        if (c < rank && c + hv[j] >= rank) *s_T = (unsigned)(tid * 8 + j);
        c += hv[j];
    }
    __syncthreads();
    return *s_T;
}

// Coarse tau for phase 0 (strided-center queries); zeroes counters + done flag.
__global__ __launch_bounds__(TPB)
void tau0_kernel(const float* __restrict__ pts, float4* __restrict__ qtau0,
                 int* __restrict__ counts, int B) {
    __shared__ unsigned s_hist[BINS];
    __shared__ unsigned s_wsum[NWAVES];
    __shared__ unsigned s_T;
    const int blk = blockIdx.x;
    const int b = blk % B, g = blk / B;
    const int gi = b * G_NUMS + g;
    const float* __restrict__ P = pts + (size_t)b * (N_PTS * 3);
    const float4* __restrict__ P4 = (const float4*)P;
    const int tid = threadIdx.x, lane = tid & 63, wid = tid >> 6;
    const float qx = P[(size_t)g * PT_STRIDE * 3 + 0];
    const float qy = P[(size_t)g * PT_STRIDE * 3 + 1];
    const float qz = P[(size_t)g * PT_STRIDE * 3 + 2];

    for (int j = tid; j < BINS; j += TPB) s_hist[j] = 0u;
    if (tid == 0) s_T = 0u;
    __syncthreads();
    for (int grp = tid; grp < SAMPLE_GRPS; grp += TPB) {
        float4 f0 = P4[3 * grp + 0];
        float4 f1 = P4[3 * grp + 1];
        float4 f2 = P4[3 * grp + 2];
        atomicAdd(&s_hist[__float_as_uint(dist2f(f0.x, f0.y, f0.z, qx, qy, qz)) >> SHIFT], 1u);
        atomicAdd(&s_hist[__float_as_uint(dist2f(f0.w, f1.x, f1.y, qx, qy, qz)) >> SHIFT], 1u);
        atomicAdd(&s_hist[__float_as_uint(dist2f(f1.z, f1.w, f2.x, qx, qy, qz)) >> SHIFT], 1u);
        atomicAdd(&s_hist[__float_as_uint(dist2f(f2.y, f2.z, f2.w, qx, qy, qz)) >> SHIFT], 1u);
    }
    __syncthreads();
    unsigned Tc = find_bin(s_hist, s_wsum, &s_T, RANK_CUT, tid, lane, wid);
    unsigned tau = (Tc >= BINS - 1) ? 0xFFFFFFFFu : ((Tc + 1) << SHIFT);
    if (tid == 0) {
        qtau0[gi] = make_float4(qx, qy, qz, __uint_as_float(tau));
        counts[gi] = 0;
        if (gi == 0) counts[DONE_IDX] = 0;   // tail-block done counter
    }
}

// Filter: block stages a 2048-pt tile into LDS once; each wave holds 4 queries
// in registers and streams the tile. Ballot-compacted writes, one global
// atomic per wave-hit-group. Each global point is read exactly once.
__global__ __launch_bounds__(TPB)
void filter_kernel(const float* __restrict__ pts, const float4* __restrict__ qtau,
                   int* __restrict__ counts, uint2* __restrict__ surv, int B) {
    __shared__ float4 s_pts[TILE];      // 32 KB
    __shared__ float4 s_qt[G_NUMS];

    const int blk = blockIdx.x;
    const int b = blk % B;              // batch pinned to XCD (blk%8)
    const int tile = blk / B;           // 0..63
    const int base = tile * TILE;
    const float4* __restrict__ P4 = (const float4*)(pts + (size_t)b * (N_PTS * 3));
    const int tid = threadIdx.x;
    const int lane = tid & 63, wid = tid >> 6;

    if (tid < G_NUMS) s_qt[tid] = qtau[b * G_NUMS + tid];
    // stage tile: 4 points per thread (3 packed float4 -> 4 padded float4)
    {
        const int t3 = tile * (TILE * 3 / 4) + 3 * tid;
        float4 f0 = P4[t3 + 0];
        float4 f1 = P4[t3 + 1];
        float4 f2 = P4[t3 + 2];
        s_pts[4 * tid + 0] = make_float4(f0.x, f0.y, f0.z, 0.f);
        s_pts[4 * tid + 1] = make_float4(f0.w, f1.x, f1.y, 0.f);
        s_pts[4 * tid + 2] = make_float4(f1.z, f1.w, f2.x, 0.f);
        s_pts[4 * tid + 3] = make_float4(f2.y, f2.z, f2.w, 0.f);
    }
    __syncthreads();

    // this wave's queries (<=4), registers; invalid slots get tau=0 (never hit)
    float qx[4], qy[4], qz[4];
    unsigned tq[4];
    int cgi[4];
#pragma unroll
    for (int j = 0; j < 4; ++j) {
        int g = wid + NWAVES * j;
        if (g < G_NUMS) {
            float4 qt = s_qt[g];
            qx[j] = qt.x; qy[j] = qt.y; qz[j] = qt.z;
            tq[j] = __float_as_uint(qt.w);
            cgi[j] = b * G_NUMS + g;
        } else { qx[j] = qy[j] = qz[j] = 0.f; tq[j] = 0u; cgi[j] = 0; }
    }

    for (int p = lane; p < TILE; p += 64) {     // uniform trip count: all lanes
        float4 pt = s_pts[p];
#pragma unroll
        for (int j = 0; j < 4; ++j) {
            unsigned u = __float_as_uint(dist2f(pt.x, pt.y, pt.z, qx[j], qy[j], qz[j]));
            unsigned long long mask = __ballot(u < tq[j]);
            if (mask) {
                int leader = __ffsll((unsigned long long)mask) - 1;
                int bp = 0;
                if (lane == leader) bp = atomicAdd(&counts[cgi[j]], __popcll(mask));
                bp = __shfl(bp, leader);
                if (u < tq[j]) {
                    int pos = bp + __popcll(mask & ((1ull << lane) - 1ull));
                    if (pos < CAP)
                        surv[(size_t)cgi[j] * CAP + pos] =
                            make_uint2(u, (unsigned)(base + p));
                }
            }
        }
    }
}

// ---- 3x3 symmetric eigensolve (Jacobi, double) ----
__device__ void eig3(const float cf[6], double lam_out[3], double dir_out[3]) {
    double a[3][3], v[3][3];
    a[0][0] = cf[0]; a[0][1] = cf[1]; a[0][2] = cf[2];
    a[1][0] = cf[1]; a[1][1] = cf[3]; a[1][2] = cf[4];
    a[2][0] = cf[2]; a[2][1] = cf[4]; a[2][2] = cf[5];
    for (int i = 0; i < 3; i++)
        for (int j = 0; j < 3; j++) v[i][j] = (i == j) ? 1.0 : 0.0;

    for (int sweep = 0; sweep < 12; sweep++) {
        double off = a[0][1] * a[0][1] + a[0][2] * a[0][2] + a[1][2] * a[1][2];
        if (off == 0.0) break;
        for (int p = 0; p < 2; p++) {
            for (int q = p + 1; q < 3; q++) {
                double apq = a[p][q];
                if (apq == 0.0) continue;
                double app = a[p][p], aqq = a[q][q];
                double theta = (aqq - app) / (2.0 * apq);
                double t = (theta >= 0.0 ? 1.0 : -1.0) /
                           (fabs(theta) + sqrt(theta * theta + 1.0));
                double c = 1.0 / sqrt(t * t + 1.0);
                double s = t * c;
                a[p][p] = app - t * apq;
                a[q][q] = aqq + t * apq;
                a[p][q] = 0.0; a[q][p] = 0.0;
                for (int r = 0; r < 3; r++) {
                    if (r == p || r == q) continue;
                    double arp = a[r][p], arq = a[r][q];
                    a[r][p] = c * arp - s * arq; a[p][r] = a[r][p];
                    a[r][q] = s * arp + c * arq; a[q][r] = a[r][q];
                }
                for (int r = 0; r < 3; r++) {
                    double vrp = v[r][p], vrq = v[r][q];
                    v[r][p] = c * vrp - s * vrq;
                    v[r][q] = s * vrp + c * vrq;
                }
            }
        }
    }
    double l0 = a[0][0], l1 = a[1][1], l2 = a[2][2];
    int i0 = 0, i1 = 1, i2 = 2;
    if (l0 > l1) { double t = l0; l0 = l1; l1 = t; int ti = i0; i0 = i1; i1 = ti; }
    if (l1 > l2) { double t = l1; l1 = l2; l2 = t; int ti = i1; i1 = i2; i2 = ti; }
    if (l0 > l1) { double t = l0; l0 = l1; l1 = t; int ti = i0; i0 = i1; i1 = ti; }
    lam_out[0] = l0; lam_out[1] = l1; lam_out[2] = l2;
    dir_out[0] = v[0][i2]; dir_out[1] = v[1][i2]; dir_out[2] = v[2][i2];
}

// Exact top-100 among survivors. PHASE 0: mean + tau1 + reset counts.
// PHASE 1: covariance, then tail-block finalize (device-scope handshake).
template <int PHASE>
__global__ __launch_bounds__(TPB)
void select_kernel(const float* __restrict__ pts,
                   const float4* __restrict__ qtau_cur,
                   float4* __restrict__ qtau_next,
                   const uint2* __restrict__ surv, int* __restrict__ counts,
                   float* __restrict__ gmeans, float* __restrict__ covs,
                   float* __restrict__ out, int B) {
    __shared__ unsigned s_hist[BINS];
    __shared__ unsigned s_wsum[NWAVES];
    __shared__ unsigned s_T;
    __shared__ int s_nd, s_nt;
    __shared__ int s_sel[G_SIZE];
    __shared__ unsigned s_tu[TIE_CAP];
    __shared__ int s_ti[TIE_CAP];
    __shared__ float s_acc[3], s_cov[6];
    __shared__ int s_last;
    __shared__ float s_dir[256][3];
    __shared__ float s_gm[256][3];
    __shared__ float s_pe[NWAVES], s_ps[NWAVES];

    const int blk = blockIdx.x;
    const int b = blk % B, g = blk / B;
    const int gi = b * G_NUMS + g;
    const int NG = B * G_NUMS;
    const float* __restrict__ P = pts + (size_t)b * (N_PTS * 3);
    const float4* __restrict__ P4 = (const float4*)P;
    const int tid = threadIdx.x, lane = tid & 63, wid = tid >> 6;

    const float4 qt = qtau_cur[gi];
    const unsigned tau = __float_as_uint(qt.w);
    int S = counts[gi]; if (S > CAP) S = CAP;
    const uint2* __restrict__ sv = surv + (size_t)gi * CAP;

    for (int j = tid; j < BINS; j += TPB) s_hist[j] = 0u;
    if (tid == 0) { s_T = 0u; s_nd = 0; s_nt = 0; }
    if (tid < 3) s_acc[tid] = 0.f;
    if (tid < 6) s_cov[tid] = 0.f;
    __syncthreads();

    unsigned hb = 32u - (unsigned)__clz(tau - 1u);
    unsigned sh = hb > 12u ? hb - 12u : 0u;
    for (int i = tid; i < S; i += TPB) atomicAdd(&s_hist[sv[i].x >> sh], 1u);
    __syncthreads();
    unsigned T2 = find_bin(s_hist, s_wsum, &s_T, G_SIZE, tid, lane, wid);
    const unsigned lo = T2 << sh;

    for (int i = tid; i < S; i += TPB) {
        unsigned u = sv[i].x;
        if (u < lo) {
            int p = atomicAdd(&s_nd, 1);
            if (p < G_SIZE) s_sel[p] = (int)sv[i].y;
        } else if ((u >> sh) == T2) {
            int p = atomicAdd(&s_nt, 1);
            if (p < TIE_CAP) { s_tu[p] = u; s_ti[p] = (int)sv[i].y; }
        }
    }
    __syncthreads();
    if (tid == 0) {
        int nd = s_nd; if (nd > G_SIZE) nd = G_SIZE;
        int need = G_SIZE - nd;
        int ec = s_nt; if (ec > TIE_CAP) ec = TIE_CAP;
        for (int a = 0; a < need && a < ec; ++a) {
            int best = a;
            for (int j = a + 1; j < ec; ++j)
                if (s_tu[j] < s_tu[best] ||
                    (s_tu[j] == s_tu[best] && s_ti[j] < s_ti[best])) best = j;
            unsigned tu = s_tu[best]; s_tu[best] = s_tu[a]; s_tu[a] = tu;
            int ti = s_ti[best]; s_ti[best] = s_ti[a]; s_ti[a] = ti;
            s_sel[nd + a] = s_ti[a];
        }
    }
    __syncthreads();

    float px = 0.f, py = 0.f, pz = 0.f;
    if (tid < G_SIZE) {
        const float* pp = P + 3 * (size_t)s_sel[tid];
        px = pp[0]; py = pp[1]; pz = pp[2];
        atomicAdd(&s_acc[0], px);
        atomicAdd(&s_acc[1], py);
        atomicAdd(&s_acc[2], pz);
    }
    __syncthreads();
    const float mx = s_acc[0] * (1.0f / G_SIZE);
    const float my = s_acc[1] * (1.0f / G_SIZE);
    const float mz = s_acc[2] * (1.0f / G_SIZE);

    if (PHASE == 0) {
        if (tid < 3) gmeans[gi * 3 + tid] = (tid == 0 ? mx : tid == 1 ? my : mz);
        // tau1 via sample scan against the mean query
        for (int j = tid; j < BINS; j += TPB) s_hist[j] = 0u;
        if (tid == 0) s_T = 0u;
        __syncthreads();
        for (int grp = tid; grp < SAMPLE_GRPS; grp += TPB) {
            float4 f0 = P4[3 * grp + 0];
            float4 f1 = P4[3 * grp + 1];
            float4 f2 = P4[3 * grp + 2];
            atomicAdd(&s_hist[__float_as_uint(dist2f(f0.x, f0.y, f0.z, mx, my, mz)) >> SHIFT], 1u);
            atomicAdd(&s_hist[__float_as_uint(dist2f(f0.w, f1.x, f1.y, mx, my, mz)) >> SHIFT], 1u);
            atomicAdd(&s_hist[__float_as_uint(dist2f(f1.z, f1.w, f2.x, mx, my, mz)) >> SHIFT], 1u);
            atomicAdd(&s_hist[__float_as_uint(dist2f(f2.y, f2.z, f2.w, mx, my, mz)) >> SHIFT], 1u);
        }
        __syncthreads();
        unsigned Tc = find_bin(s_hist, s_wsum, &s_T, RANK_CUT, tid, lane, wid);
        unsigned tau1 = (Tc >= BINS - 1) ? 0xFFFFFFFFu : ((Tc + 1) << SHIFT);
        if (tid == 0) {
            qtau_next[gi] = make_float4(mx, my, mz, __uint_as_float(tau1));
            counts[gi] = 0;            // reset for phase-1 filter
        }
    } else {
        if (tid < G_SIZE) {
            float x = px - mx, y = py - my, z = pz - mz;
            atomicAdd(&s_cov[0], x * x);
            atomicAdd(&s_cov[1], x * y);
            atomicAdd(&s_cov[2], x * z);
            atomicAdd(&s_cov[3], y * y);
            atomicAdd(&s_cov[4], y * z);
            atomicAdd(&s_cov[5], z * z);
        }
        __syncthreads();
        if (tid < 6) covs[gi * 6 + tid] = s_cov[tid] * (1.0f / G_SIZE);

        // ---- tail-block handshake: last block to finish does the finalize ----
        __syncthreads();
        if (tid == 0) {
            __threadfence();           // release covs to device scope
            int old = __hip_atomic_fetch_add(&counts[DONE_IDX], 1,
                                             __ATOMIC_ACQ_REL,
                                             __HIP_MEMORY_SCOPE_AGENT);
            s_last = (old == NG - 1) ? 1 : 0;
        }
        __syncthreads();
        if (!s_last) return;
        __threadfence();               // acquire before reading other blocks' covs

        float et = 0.f;
        if (tid < NG) {
            float cf[6];
#pragma unroll
            for (int j = 0; j < 6; j++)
                cf[j] = __hip_atomic_load(&covs[tid * 6 + j], __ATOMIC_RELAXED,
                                          __HIP_MEMORY_SCOPE_AGENT);
            double lam[3], dir[3];
            eig3(cf, lam, dir);
            double denom = lam[0] + lam[1] + lam[2] + 1e-9;
            et = (float)((lam[2] - lam[1]) / denom);
            s_dir[tid][0] = (float)dir[0];
            s_dir[tid][1] = (float)dir[1];
            s_dir[tid][2] = (float)dir[2];
            s_gm[tid][0] = gmeans[tid * 3 + 0];   // prev dispatch: plain load ok
            s_gm[tid][1] = gmeans[tid * 3 + 1];
            s_gm[tid][2] = gmeans[tid * 3 + 2];
        }
        __syncthreads();

        float st = 0.f;
        if (tid < NG) {
            int bb = tid / G_NUMS, gg0 = tid % G_NUMS;
            float gx = s_gm[tid][0], gy = s_gm[tid][1], gz = s_gm[tid][2];
            float bd = 3.4e38f; int bj = 0;
            for (int gg = 0; gg < G_NUMS; gg++) {
                if (gg == gg0) continue;
                int o = bb * G_NUMS + gg;
                float dx = gx - s_gm[o][0];
                float dy = gy - s_gm[o][1];
                float dz = gz - s_gm[o][2];
                float d = dx * dx + dy * dy + dz * dz;
                if (d < bd) { bd = d; bj = gg; }
            }
            int o = bb * G_NUMS + bj;
            float cosv = s_dir[tid][0] * s_dir[o][0] +
                         s_dir[tid][1] * s_dir[o][1] +
                         s_dir[tid][2] * s_dir[o][2];
            st = 1.f - cosv * cosv;
        }

        float e = et, s2 = st;
#pragma unroll
        for (int off = 32; off > 0; off >>= 1) {
            e += __shfl_down(e, off);
            s2 += __shfl_down(s2, off);
        }
        if (lane == 0) { s_pe[wid] = e; s_ps[wid] = s2; }
        __syncthreads();
        if (tid == 0) {
            float se = 0.f, ss = 0.f;
            for (int w = 0; w < NWAVES; w++) { se += s_pe[w]; ss += s_ps[w]; }
            out[0] = -se / (float)B + ss / (float)NG;
        }
    }
}

extern "C" void kernel_launch(void* const* d_in, const int* in_sizes, int n_in,
                              void* d_out, int out_size, void* d_ws, size_t ws_size,
                              hipStream_t stream) {
    const float* pts = (const float*)d_in[0];
    float* out = (float*)d_out;
    int B = in_sizes[0] / (N_PTS * 3);   // 8
    const int NG = B * G_NUMS;           // 240

    float4* qtau0 = (float4*)d_ws;                 // NG
    float4* qtau1 = qtau0 + NG;                    // NG
    float* gmeans = (float*)(qtau1 + NG);          // NG*3
    float* covs = gmeans + NG * 3;                 // NG*6
    int* counts = (int*)(covs + NG * 6);           // 256 ints (incl. done flag)
    uint2* surv = (uint2*)(counts + 256);          // NG*CAP*8 B (~3.9 MB)

    const int FBLK = B * (N_PTS / TILE);           // 512
    tau0_kernel<<<NG, TPB, 0, stream>>>(pts, qtau0, counts, B);
    filter_kernel<<<FBLK, TPB, 0, stream>>>(pts, qtau0, counts, surv, B);
    select_kernel<0><<<NG, TPB, 0, stream>>>(pts, qtau0, qtau1, surv, counts,
                                             gmeans, covs, out, B);
    filter_kernel<<<FBLK, TPB, 0, stream>>>(pts, qtau1, counts, surv, B);
    select_kernel<1><<<NG, TPB, 0, stream>>>(pts, qtau1, nullptr, surv, counts,
                                             gmeans, covs, out, B);
}

// Round 7
// 414.585 us; speedup vs baseline: 1.3917x; 1.3917x over previous
//
#include <hip/hip_runtime.h>
#include <math.h>

#define N_PTS     131072
#define G_NUMS    30
#define G_SIZE    100
#define PT_STRIDE (N_PTS / G_NUMS)   // 4369
#define TPB       512
#define NWAVES    8
#define BINS      4096
#define SHIFT     20
#define SAMPLE_GRPS 1024             // first 4096 points as iid sample
#define RANK_CUT  24                 // 24th-smallest sample -> tau (P(miss) ~ 1e-13)
#define CAP       1280               // survivor cap per (b,g); E~784, +17 sigma
#define CAPB      96                 // per-(block,g) LDS buffer; Poisson mean 24
#define TIE_CAP   64
#define NB        8                  // batches (fixed for this problem)
#define NCHUNK    32                 // filter chunks per batch
#define CHUNK     (N_PTS / NCHUNK)   // 4096 points per block
#define NG_TOT    (NB * G_NUMS)      // 240
// sync[] slots: [0..7]=doneF0[b], [8..15]=ready1[b], [16..23]=doneF1[b], [24]=doneAll

__device__ __forceinline__ float dist2f(float px, float py, float pz,
                                        float qx, float qy, float qz) {
    float dx = px - qx, dy = py - qy, dz = pz - qz;
    return fmaf(dx, dx, fmaf(dy, dy, dz * dz));
}

__device__ __forceinline__ unsigned aloadu(const unsigned* p) {
    return __hip_atomic_load(p, __ATOMIC_RELAXED, __HIP_MEMORY_SCOPE_AGENT);
}
__device__ __forceinline__ int aloadi(const int* p) {
    return __hip_atomic_load(p, __ATOMIC_RELAXED, __HIP_MEMORY_SCOPE_AGENT);
}

// tid 0 spins (acquire, agent scope) until *ptr >= target; then block barrier.
__device__ __forceinline__ void spin_until(const int* ptr, int target) {
    if (threadIdx.x == 0) {
        while (__hip_atomic_load(ptr, __ATOMIC_ACQUIRE, __HIP_MEMORY_SCOPE_AGENT) < target)
            __builtin_amdgcn_s_sleep(1);
    }
    __syncthreads();
    __threadfence();
}

// Smallest bin T with cumulative count >= rank. s_hist populated+synced on entry.
__device__ __forceinline__ unsigned find_bin(unsigned* s_hist, unsigned* s_wsum,
                                             unsigned* s_T, unsigned rank,
                                             int tid, int lane, int wid) {
    unsigned hv[8], csum = 0;
#pragma unroll
    for (int j = 0; j < 8; j++) { hv[j] = s_hist[tid * 8 + j]; csum += hv[j]; }
    unsigned inc = csum;
#pragma unroll
    for (int off = 1; off < 64; off <<= 1) {
        unsigned n = __shfl_up(inc, off);
        if (lane >= off) inc += n;
    }
    __syncthreads();
    if (lane == 63) s_wsum[wid] = inc;
    __syncthreads();
    unsigned base = 0;
    for (int w = 0; w < wid; w++) base += s_wsum[w];
    unsigned c = base + inc - csum;
#pragma unroll
    for (int j = 0; j < 8; j++) {
        if (c < rank && c + hv[j] >= rank) *s_T = (unsigned)(tid * 8 + j);
        c += hv[j];
    }
    __syncthreads();
    return *s_T;
}

// Sampled coarse threshold from the first 4096 points of batch P.
__device__ unsigned sample_tau(const float4* __restrict__ P4,
                               float qx, float qy, float qz,
                               unsigned* s_hist, unsigned* s_wsum, unsigned* s_T,
                               int tid, int lane, int wid) {
    for (int j = tid; j < BINS; j += TPB) s_hist[j] = 0u;
    if (tid == 0) *s_T = 0u;
    __syncthreads();
    for (int grp = tid; grp < SAMPLE_GRPS; grp += TPB) {
        float4 f0 = P4[3 * grp + 0];
        float4 f1 = P4[3 * grp + 1];
        float4 f2 = P4[3 * grp + 2];
        atomicAdd(&s_hist[__float_as_uint(dist2f(f0.x, f0.y, f0.z, qx, qy, qz)) >> SHIFT], 1u);
        atomicAdd(&s_hist[__float_as_uint(dist2f(f0.w, f1.x, f1.y, qx, qy, qz)) >> SHIFT], 1u);
        atomicAdd(&s_hist[__float_as_uint(dist2f(f1.z, f1.w, f2.x, qx, qy, qz)) >> SHIFT], 1u);
        atomicAdd(&s_hist[__float_as_uint(dist2f(f2.y, f2.z, f2.w, qx, qy, qz)) >> SHIFT], 1u);
    }
    __syncthreads();
    unsigned Tc = find_bin(s_hist, s_wsum, s_T, RANK_CUT, tid, lane, wid);
    return (Tc >= BINS - 1) ? 0xFFFFFFFFu : ((Tc + 1) << SHIFT);
}

// D1: per-(b,g) coarse tau + zero all counters/sync slots.
__global__ __launch_bounds__(TPB)
void init_tau0_kernel(const float* __restrict__ pts, unsigned* __restrict__ qtau0,
                      int* __restrict__ count0, int* __restrict__ count1,
                      int* __restrict__ sync) {
    __shared__ unsigned s_hist[BINS];
    __shared__ unsigned s_wsum[NWAVES];
    __shared__ unsigned s_T;
    const int blk = blockIdx.x;
    const int b = blk % NB, g = blk / NB;
    const int gi = b * G_NUMS + g;
    const float* __restrict__ P = pts + (size_t)b * (N_PTS * 3);
    const int tid = threadIdx.x, lane = tid & 63, wid = tid >> 6;

    if (tid == 0) { count0[gi] = 0; count1[gi] = 0; }
    if (blk == 0 && tid < 32) sync[tid] = 0;

    const float qx = P[(size_t)g * PT_STRIDE * 3 + 0];
    const float qy = P[(size_t)g * PT_STRIDE * 3 + 1];
    const float qz = P[(size_t)g * PT_STRIDE * 3 + 2];
    unsigned tau = sample_tau((const float4*)P, qx, qy, qz,
                              s_hist, s_wsum, &s_T, tid, lane, wid);
    if (tid == 0) {
        qtau0[gi * 4 + 0] = __float_as_uint(qx);
        qtau0[gi * 4 + 1] = __float_as_uint(qy);
        qtau0[gi * 4 + 2] = __float_as_uint(qz);
        qtau0[gi * 4 + 3] = tau;
    }
}

// Filter this block's 4096-pt SoA tile against 30 queries; survivors -> per-g
// LDS buffers (r4-proven, conflict-free) -> one flush atomic per (block,g).
__device__ void filter_chunk(const float* s_x, const float* s_y, const float* s_z,
                             const float4* s_qt, int* s_cnt, uint2 (*s_buf)[CAPB],
                             int base, int* __restrict__ countArr,
                             uint2* __restrict__ survArr, int bg0,
                             int tid, int lane, int wid) {
    for (int g0 = 0; g0 < G_NUMS; g0 += 6) {
        // 8 points per thread, lane-stride-1 LDS reads (conflict-free), hoisted
        float x[8], y[8], z[8];
#pragma unroll
        for (int k = 0; k < 8; k++) {
            int p = tid + k * TPB;
            x[k] = s_x[p]; y[k] = s_y[p]; z[k] = s_z[p];
        }
#pragma unroll
        for (int g = g0; g < g0 + 6; ++g) {
            float4 qt = s_qt[g];
            const unsigned taub = __float_as_uint(qt.w);
#pragma unroll
            for (int k = 0; k < 8; k++) {
                float d = dist2f(x[k], y[k], z[k], qt.x, qt.y, qt.z);
                unsigned u = __float_as_uint(d);
                if (u < taub) {
                    int p = atomicAdd(&s_cnt[g], 1);
                    if (p < CAPB)
                        s_buf[g][p] = make_uint2(u, (unsigned)(base + tid + k * TPB));
                }
            }
        }
    }
    __syncthreads();
    for (int g = wid; g < G_NUMS; g += NWAVES) {
        int n = s_cnt[g]; if (n > CAPB) n = CAPB;
        int bb = 0;
        if (lane == 0 && n > 0)
            bb = __hip_atomic_fetch_add(&countArr[bg0 + g], n,
                                        __ATOMIC_RELAXED, __HIP_MEMORY_SCOPE_AGENT);
        bb = __shfl(bb, 0);
        for (int i = lane; i < n; i += 64) {
            int pos = bb + i;
            if (pos < CAP) survArr[(size_t)(bg0 + g) * CAP + pos] = s_buf[g][i];
        }
    }
}

// Exact top-100 among survivors (agent-scope reads) -> s_sel[100].
__device__ void select100(const uint2* __restrict__ sv, int S, unsigned tau,
                          unsigned* s_hist, unsigned* s_wsum, unsigned* s_T,
                          int* s_nd, int* s_nt, int* s_sel,
                          unsigned* s_tu, int* s_ti,
                          int tid, int lane, int wid) {
    for (int j = tid; j < BINS; j += TPB) s_hist[j] = 0u;
    if (tid == 0) { *s_T = 0u; *s_nd = 0; *s_nt = 0; }
    __syncthreads();
    unsigned hb = 32u - (unsigned)__clz(tau - 1u);
    unsigned sh = hb > 12u ? hb - 12u : 0u;
    const unsigned* svu = (const unsigned*)sv;
    for (int i = tid; i < S; i += TPB)
        atomicAdd(&s_hist[aloadu(&svu[2 * i]) >> sh], 1u);
    __syncthreads();
    unsigned T2 = find_bin(s_hist, s_wsum, s_T, G_SIZE, tid, lane, wid);
    const unsigned lo = T2 << sh;
    for (int i = tid; i < S; i += TPB) {
        unsigned u = aloadu(&svu[2 * i]);
        unsigned id = aloadu(&svu[2 * i + 1]);
        if (u < lo) {
            int p = atomicAdd(s_nd, 1);
            if (p < G_SIZE) s_sel[p] = (int)id;
        } else if ((u >> sh) == T2) {
            int p = atomicAdd(s_nt, 1);
            if (p < TIE_CAP) { s_tu[p] = u; s_ti[p] = (int)id; }
        }
    }
    __syncthreads();
    if (tid == 0) {
        int nd = *s_nd; if (nd > G_SIZE) nd = G_SIZE;
        int need = G_SIZE - nd;
        int ec = *s_nt; if (ec > TIE_CAP) ec = TIE_CAP;
        for (int a = 0; a < need && a < ec; ++a) {
            int best = a;
            for (int j = a + 1; j < ec; ++j)
                if (s_tu[j] < s_tu[best] ||
                    (s_tu[j] == s_tu[best] && s_ti[j] < s_ti[best])) best = j;
            unsigned tu = s_tu[best]; s_tu[best] = s_tu[a]; s_tu[a] = tu;
            int ti = s_ti[best]; s_ti[best] = s_ti[a]; s_ti[a] = ti;
            s_sel[nd + a] = s_ti[a];
        }
    }
    __syncthreads();
}

// ---- 3x3 symmetric eigensolve (Jacobi, double) ----
__device__ void eig3(const float cf[6], double lam_out[3], double dir_out[3]) {
    double a[3][3], v[3][3];
    a[0][0] = cf[0]; a[0][1] = cf[1]; a[0][2] = cf[2];
    a[1][0] = cf[1]; a[1][1] = cf[3]; a[1][2] = cf[4];
    a[2][0] = cf[2]; a[2][1] = cf[4]; a[2][2] = cf[5];
    for (int i = 0; i < 3; i++)
        for (int j = 0; j < 3; j++) v[i][j] = (i == j) ? 1.0 : 0.0;
    for (int sweep = 0; sweep < 12; sweep++) {
        double off = a[0][1] * a[0][1] + a[0][2] * a[0][2] + a[1][2] * a[1][2];
        if (off == 0.0) break;
        for (int p = 0; p < 2; p++) {
            for (int q = p + 1; q < 3; q++) {
                double apq = a[p][q];
                if (apq == 0.0) continue;
                double app = a[p][p], aqq = a[q][q];
                double theta = (aqq - app) / (2.0 * apq);
                double t = (theta >= 0.0 ? 1.0 : -1.0) /
                           (fabs(theta) + sqrt(theta * theta + 1.0));
                double c = 1.0 / sqrt(t * t + 1.0);
                double s = t * c;
                a[p][p] = app - t * apq;
                a[q][q] = aqq + t * apq;
                a[p][q] = 0.0; a[q][p] = 0.0;
                for (int r = 0; r < 3; r++) {
                    if (r == p || r == q) continue;
                    double arp = a[r][p], arq = a[r][q];
                    a[r][p] = c * arp - s * arq; a[p][r] = a[r][p];
                    a[r][q] = s * arp + c * arq; a[q][r] = a[r][q];
                }
                for (int r = 0; r < 3; r++) {
                    double vrp = v[r][p], vrq = v[r][q];
                    v[r][p] = c * vrp - s * vrq;
                    v[r][q] = s * vrp + c * vrq;
                }
            }
        }
    }
    double l0 = a[0][0], l1 = a[1][1], l2 = a[2][2];
    int i0 = 0, i1 = 1, i2 = 2;
    if (l0 > l1) { double t = l0; l0 = l1; l1 = t; int ti = i0; i0 = i1; i1 = ti; }
    if (l1 > l2) { double t = l1; l1 = l2; l2 = t; int ti = i1; i1 = i2; i2 = ti; }
    if (l0 > l1) { double t = l0; l0 = l1; l1 = t; int ti = i0; i0 = i1; i1 = ti; }
    lam_out[0] = l0; lam_out[1] = l1; lam_out[2] = l2;
    dir_out[0] = v[0][i2]; dir_out[1] = v[1][i2]; dir_out[2] = v[2][i2];
}

// D2: filter0 -> select0+tau1 -> filter1 -> select1+cov -> tail finalize.
// grid = 256 (1 block/CU: co-residency by capacity; spins only wait on work
// already started by resident blocks).
__global__ __launch_bounds__(TPB)
void mono2_kernel(const float* __restrict__ pts, float* __restrict__ out,
                  const unsigned* __restrict__ qtau0, unsigned* __restrict__ qtau1,
                  unsigned* __restrict__ gmeans, unsigned* __restrict__ covs,
                  int* __restrict__ count0, int* __restrict__ count1,
                  int* __restrict__ sync,
                  uint2* __restrict__ surv0, uint2* __restrict__ surv1) {
    __shared__ float s_x[CHUNK], s_y[CHUNK], s_z[CHUNK];   // 48 KB SoA tile
    __shared__ unsigned s_hist[BINS];                      // 16 KB
    __shared__ uint2 s_buf[G_NUMS][CAPB];                  // 22.5 KB
    __shared__ float4 s_qt[G_NUMS];
    __shared__ int s_cnt[G_NUMS];
    __shared__ unsigned s_wsum[NWAVES];
    __shared__ unsigned s_T;
    __shared__ int s_nd, s_nt;
    __shared__ int s_sel[G_SIZE];
    __shared__ unsigned s_tu[TIE_CAP];
    __shared__ int s_ti[TIE_CAP];
    __shared__ float s_acc[3], s_cov[6];
    __shared__ int s_last;
    __shared__ float s_dir[NG_TOT][3];
    __shared__ float s_gm[NG_TOT][3];
    __shared__ float s_pe[NWAVES], s_ps[NWAVES];

    const int tid = threadIdx.x, lane = tid & 63, wid = tid >> 6;
    const int blk = blockIdx.x;
    const int b = blk & 7, chunk = blk >> 3;
    const bool isSel = (chunk < G_NUMS);     // 240 selector blocks, g = chunk
    const int gi = b * G_NUMS + chunk;       // valid when isSel
    const float* __restrict__ P = pts + (size_t)b * (N_PTS * 3);
    const int bg0 = b * G_NUMS;

    // ---- stage this block's 4096-pt tile into SoA (coalesced b32 reads) ----
    {
        const float* __restrict__ Pc = P + (size_t)chunk * CHUNK * 3;
#pragma unroll
        for (int r = 0; r < 24; r++) {
            int j = r * TPB + tid;
            float v = Pc[j];
            int p = j / 3, c = j - 3 * p;
            if (c == 0) s_x[p] = v; else if (c == 1) s_y[p] = v; else s_z[p] = v;
        }
    }
    // ---- phase F0 ----
    if (tid < G_NUMS) {
        const unsigned* qt = &qtau0[(bg0 + tid) * 4];   // cross-dispatch: plain
        s_qt[tid] = make_float4(__uint_as_float(qt[0]), __uint_as_float(qt[1]),
                                __uint_as_float(qt[2]), __uint_as_float(qt[3]));
        s_cnt[tid] = 0;
    }
    __syncthreads();
    filter_chunk(s_x, s_y, s_z, s_qt, s_cnt, s_buf, chunk * CHUNK,
                 count0, surv0, bg0, tid, lane, wid);
    __threadfence();
    if (tid == 0)
        __hip_atomic_fetch_add(&sync[b], 1, __ATOMIC_ACQ_REL, __HIP_MEMORY_SCOPE_AGENT);

    // ---- phase S0 (selectors): exact select -> mean -> tau1 ----
    if (isSel) {
        spin_until(&sync[b], NCHUNK);
        int S = aloadi(&count0[gi]); if (S > CAP) S = CAP;
        unsigned tau = __float_as_uint(s_qt[chunk].w);
        select100(surv0 + (size_t)gi * CAP, S, tau, s_hist, s_wsum, &s_T,
                  &s_nd, &s_nt, s_sel, s_tu, s_ti, tid, lane, wid);
        if (tid < 3) s_acc[tid] = 0.f;
        __syncthreads();
        float px = 0.f, py = 0.f, pz = 0.f;
        if (tid < G_SIZE) {
            const float* pp = P + 3 * (size_t)s_sel[tid];
            px = pp[0]; py = pp[1]; pz = pp[2];
            atomicAdd(&s_acc[0], px);
            atomicAdd(&s_acc[1], py);
            atomicAdd(&s_acc[2], pz);
        }
        __syncthreads();
        const float mx = s_acc[0] * (1.0f / G_SIZE);
        const float my = s_acc[1] * (1.0f / G_SIZE);
        const float mz = s_acc[2] * (1.0f / G_SIZE);
        if (tid < 3) gmeans[gi * 3 + tid] =
            __float_as_uint(tid == 0 ? mx : tid == 1 ? my : mz);
        unsigned tau1 = sample_tau((const float4*)P, mx, my, mz,
                                   s_hist, s_wsum, &s_T, tid, lane, wid);
        if (tid == 0) {
            qtau1[gi * 4 + 0] = __float_as_uint(mx);
            qtau1[gi * 4 + 1] = __float_as_uint(my);
            qtau1[gi * 4 + 2] = __float_as_uint(mz);
            qtau1[gi * 4 + 3] = tau1;
        }
        __threadfence();
        if (tid == 0)
            __hip_atomic_fetch_add(&sync[8 + b], 1, __ATOMIC_ACQ_REL,
                                   __HIP_MEMORY_SCOPE_AGENT);
    }

    // ---- phase F1 (all blocks) ----
    spin_until(&sync[8 + b], G_NUMS);
    if (tid < G_NUMS) {
        const unsigned* qt = &qtau1[(bg0 + tid) * 4];   // same-dispatch: agent loads
        s_qt[tid] = make_float4(__uint_as_float(aloadu(&qt[0])),
                                __uint_as_float(aloadu(&qt[1])),
                                __uint_as_float(aloadu(&qt[2])),
                                __uint_as_float(aloadu(&qt[3])));
        s_cnt[tid] = 0;
    }
    __syncthreads();
    filter_chunk(s_x, s_y, s_z, s_qt, s_cnt, s_buf, chunk * CHUNK,
                 count1, surv1, bg0, tid, lane, wid);
    __threadfence();
    if (tid == 0)
        __hip_atomic_fetch_add(&sync[16 + b], 1, __ATOMIC_ACQ_REL,
                               __HIP_MEMORY_SCOPE_AGENT);
    if (!isSel) return;

    // ---- phase S1 (selectors): exact select -> covariance ----
    spin_until(&sync[16 + b], NCHUNK);
    {
        int S = aloadi(&count1[gi]); if (S > CAP) S = CAP;
        unsigned tau = __float_as_uint(s_qt[chunk].w);
        select100(surv1 + (size_t)gi * CAP, S, tau, s_hist, s_wsum, &s_T,
                  &s_nd, &s_nt, s_sel, s_tu, s_ti, tid, lane, wid);
        if (tid < 3) s_acc[tid] = 0.f;
        if (tid < 6) s_cov[tid] = 0.f;
        __syncthreads();
        float px = 0.f, py = 0.f, pz = 0.f;
        if (tid < G_SIZE) {
            const float* pp = P + 3 * (size_t)s_sel[tid];
            px = pp[0]; py = pp[1]; pz = pp[2];
            atomicAdd(&s_acc[0], px);
            atomicAdd(&s_acc[1], py);
            atomicAdd(&s_acc[2], pz);
        }
        __syncthreads();
        const float mx = s_acc[0] * (1.0f / G_SIZE);
        const float my = s_acc[1] * (1.0f / G_SIZE);
        const float mz = s_acc[2] * (1.0f / G_SIZE);
        if (tid < G_SIZE) {
            float x = px - mx, y = py - my, z = pz - mz;
            atomicAdd(&s_cov[0], x * x);
            atomicAdd(&s_cov[1], x * y);
            atomicAdd(&s_cov[2], x * z);
            atomicAdd(&s_cov[3], y * y);
            atomicAdd(&s_cov[4], y * z);
            atomicAdd(&s_cov[5], z * z);
        }
        __syncthreads();
        if (tid < 6) covs[gi * 6 + tid] = __float_as_uint(s_cov[tid] * (1.0f / G_SIZE));
        __threadfence();
        if (tid == 0) {
            int old = __hip_atomic_fetch_add(&sync[24], 1, __ATOMIC_ACQ_REL,
                                             __HIP_MEMORY_SCOPE_AGENT);
            s_last = (old == NG_TOT - 1) ? 1 : 0;
        }
        __syncthreads();
        if (!s_last) return;
        __threadfence();

        // ---- tail finalize (r6-proven pattern) ----
        float et = 0.f;
        if (tid < NG_TOT) {
            float cf[6];
#pragma unroll
            for (int j = 0; j < 6; j++)
                cf[j] = __uint_as_float(aloadu(&covs[tid * 6 + j]));
            double lam[3], dir[3];
            eig3(cf, lam, dir);
            double denom = lam[0] + lam[1] + lam[2] + 1e-9;
            et = (float)((lam[2] - lam[1]) / denom);
            s_dir[tid][0] = (float)dir[0];
            s_dir[tid][1] = (float)dir[1];
            s_dir[tid][2] = (float)dir[2];
            s_gm[tid][0] = __uint_as_float(aloadu(&gmeans[tid * 3 + 0]));
            s_gm[tid][1] = __uint_as_float(aloadu(&gmeans[tid * 3 + 1]));
            s_gm[tid][2] = __uint_as_float(aloadu(&gmeans[tid * 3 + 2]));
        }
        __syncthreads();
        float st = 0.f;
        if (tid < NG_TOT) {
            int bb = tid / G_NUMS, g0 = tid % G_NUMS;
            float gx = s_gm[tid][0], gy = s_gm[tid][1], gz = s_gm[tid][2];
            float bd = 3.4e38f; int bj = 0;
            for (int gg = 0; gg < G_NUMS; gg++) {
                if (gg == g0) continue;
                int o = bb * G_NUMS + gg;
                float dx = gx - s_gm[o][0];
                float dy = gy - s_gm[o][1];
                float dz = gz - s_gm[o][2];
                float d = dx * dx + dy * dy + dz * dz;
                if (d < bd) { bd = d; bj = gg; }
            }
            int o = bb * G_NUMS + bj;
            float cosv = s_dir[tid][0] * s_dir[o][0] +
                         s_dir[tid][1] * s_dir[o][1] +
                         s_dir[tid][2] * s_dir[o][2];
            st = 1.f - cosv * cosv;
        }
        float e = et, s2 = st;
#pragma unroll
        for (int off = 32; off > 0; off >>= 1) {
            e += __shfl_down(e, off);
            s2 += __shfl_down(s2, off);
        }
        if (lane == 0) { s_pe[wid] = e; s_ps[wid] = s2; }
        __syncthreads();
        if (tid == 0) {
            float se = 0.f, ss = 0.f;
            for (int w = 0; w < NWAVES; w++) { se += s_pe[w]; ss += s_ps[w]; }
            out[0] = -se / (float)NB + ss / (float)NG_TOT;
        }
    }
}

extern "C" void kernel_launch(void* const* d_in, const int* in_sizes, int n_in,
                              void* d_out, int out_size, void* d_ws, size_t ws_size,
                              hipStream_t stream) {
    const float* pts = (const float*)d_in[0];
    float* out = (float*)d_out;
    unsigned* ws = (unsigned*)d_ws;

    unsigned* qtau0 = ws;                       // 240*4
    unsigned* qtau1 = qtau0 + NG_TOT * 4;       // 240*4
    unsigned* gmeans = qtau1 + NG_TOT * 4;      // 240*3
    unsigned* covs = gmeans + NG_TOT * 3;       // 240*6
    int* count0 = (int*)(covs + NG_TOT * 6);    // 240
    int* count1 = count0 + NG_TOT;              // 240
    int* sync = count1 + NG_TOT;                // 32
    uint2* surv0 = (uint2*)(sync + 32);         // 240*CAP
    uint2* surv1 = surv0 + (size_t)NG_TOT * CAP;

    init_tau0_kernel<<<NG_TOT, TPB, 0, stream>>>(pts, qtau0, count0, count1, sync);
    mono2_kernel<<<256, TPB, 0, stream>>>(pts, out, qtau0, qtau1, gmeans, covs,
                                          count0, count1, sync, surv0, surv1);
}

// Round 8
// 204.592 us; speedup vs baseline: 2.8202x; 2.0264x over previous
//
#include <hip/hip_runtime.h>
#include <math.h>

#define N_PTS     131072
#define G_NUMS    30
#define G_SIZE    100
#define PT_STRIDE (N_PTS / G_NUMS)   // 4369
#define TPB       512                // tau0/select blocks
#define FTPB      256                // filter blocks
#define NWAVES    8
#define BINS      4096
#define SHIFT     20
#define SAMPLE_GRPS 1024             // first 4096 points as iid sample
#define RANK_CUT  24                 // 24th-smallest sample -> tau (P(miss) ~ 1e-13)
#define CAP       1280               // survivor cap per (b,g); E~768
#define CAPB      48                 // per-(block,g) LDS buffer; Poisson mean 12
#define TIE_CAP   64
#define NB        8                  // batches (fixed)
#define NCHUNK    64                 // filter chunks per batch
#define CHUNK     (N_PTS / NCHUNK)   // 2048 points per filter block
#define NG_TOT    (NB * G_NUMS)      // 240
#define DONE_IDX  NG_TOT             // done-counter slot appended to count1

__device__ __forceinline__ float dist2f(float px, float py, float pz,
                                        float qx, float qy, float qz) {
    float dx = px - qx, dy = py - qy, dz = pz - qz;
    return fmaf(dx, dx, fmaf(dy, dy, dz * dz));
}

// Smallest bin T with cumulative count >= rank. s_hist populated+synced on entry.
__device__ __forceinline__ unsigned find_bin(unsigned* s_hist, unsigned* s_wsum,
                                             unsigned* s_T, unsigned rank,
                                             int tid, int lane, int wid) {
    unsigned hv[8], csum = 0;
#pragma unroll
    for (int j = 0; j < 8; j++) { hv[j] = s_hist[tid * 8 + j]; csum += hv[j]; }
    unsigned inc = csum;
#pragma unroll
    for (int off = 1; off < 64; off <<= 1) {
        unsigned n = __shfl_up(inc, off);
        if (lane >= off) inc += n;
    }
    __syncthreads();
    if (lane == 63) s_wsum[wid] = inc;
    __syncthreads();
    unsigned base = 0;
    for (int w = 0; w < wid; w++) base += s_wsum[w];
    unsigned c = base + inc - csum;
#pragma unroll
    for (int j = 0; j < 8; j++) {
        if (c < rank && c + hv[j] >= rank) *s_T = (unsigned)(tid * 8 + j);
        c += hv[j];
    }
    __syncthreads();
    return *s_T;
}

// Sampled coarse threshold from the first 4096 points of batch P. (TPB=512)
__device__ unsigned sample_tau(const float4* __restrict__ P4,
                               float qx, float qy, float qz,
                               unsigned* s_hist, unsigned* s_wsum, unsigned* s_T,
                               int tid, int lane, int wid) {
    for (int j = tid; j < BINS; j += TPB) s_hist[j] = 0u;
    if (tid == 0) *s_T = 0u;
    __syncthreads();
    for (int grp = tid; grp < SAMPLE_GRPS; grp += TPB) {
        float4 f0 = P4[3 * grp + 0];
        float4 f1 = P4[3 * grp + 1];
        float4 f2 = P4[3 * grp + 2];
        atomicAdd(&s_hist[__float_as_uint(dist2f(f0.x, f0.y, f0.z, qx, qy, qz)) >> SHIFT], 1u);
        atomicAdd(&s_hist[__float_as_uint(dist2f(f0.w, f1.x, f1.y, qx, qy, qz)) >> SHIFT], 1u);
        atomicAdd(&s_hist[__float_as_uint(dist2f(f1.z, f1.w, f2.x, qx, qy, qz)) >> SHIFT], 1u);
        atomicAdd(&s_hist[__float_as_uint(dist2f(f2.y, f2.z, f2.w, qx, qy, qz)) >> SHIFT], 1u);
    }
    __syncthreads();
    unsigned Tc = find_bin(s_hist, s_wsum, s_T, RANK_CUT, tid, lane, wid);
    return (Tc >= BINS - 1) ? 0xFFFFFFFFu : ((Tc + 1) << SHIFT);
}

// D1: per-(b,g) coarse tau0 + zero both count arrays and the done counter.
__global__ __launch_bounds__(TPB)
void tau0_kernel(const float* __restrict__ pts, float4* __restrict__ qtau0,
                 int* __restrict__ count0, int* __restrict__ count1) {
    __shared__ unsigned s_hist[BINS];
    __shared__ unsigned s_wsum[NWAVES];
    __shared__ unsigned s_T;
    const int blk = blockIdx.x;
    const int b = blk % NB, g = blk / NB;
    const int gi = b * G_NUMS + g;
    const float* __restrict__ P = pts + (size_t)b * (N_PTS * 3);
    const int tid = threadIdx.x, lane = tid & 63, wid = tid >> 6;

    if (tid == 0) { count0[gi] = 0; count1[gi] = 0; }
    if (blk == 0 && tid == 0) count1[DONE_IDX] = 0;

    const float qx = P[(size_t)g * PT_STRIDE * 3 + 0];
    const float qy = P[(size_t)g * PT_STRIDE * 3 + 1];
    const float qz = P[(size_t)g * PT_STRIDE * 3 + 2];
    unsigned tau = sample_tau((const float4*)P, qx, qy, qz,
                              s_hist, s_wsum, &s_T, tid, lane, wid);
    if (tid == 0)
        qtau0[gi] = make_float4(qx, qy, qz, __uint_as_float(tau));
}

// Filter: 512 blocks x 256 thr, 4 blocks/CU. SoA LDS tile staged once; 8 points
// per thread hoisted to registers; survivors -> per-g LDS buffers (r4-proven,
// conflict-free) -> one global flush atomic per (block,g). Points read once.
__global__ __launch_bounds__(FTPB)
void filter_kernel(const float* __restrict__ pts, const float4* __restrict__ qtau,
                   int* __restrict__ counts, uint2* __restrict__ surv) {
    __shared__ float s_x[CHUNK], s_y[CHUNK], s_z[CHUNK];   // 24 KB SoA
    __shared__ uint2 s_buf[G_NUMS][CAPB];                  // 11.25 KB
    __shared__ float4 s_qt[G_NUMS];
    __shared__ int s_cnt[G_NUMS];

    const int blk = blockIdx.x;
    const int b = blk & 7;              // batch pinned to XCD
    const int chunk = blk >> 3;         // 0..63
    const int bg0 = b * G_NUMS;
    const int base = chunk * CHUNK;
    const float* __restrict__ Pc =
        pts + (size_t)b * (N_PTS * 3) + (size_t)base * 3;
    const int tid = threadIdx.x;
    const int lane = tid & 63, wid = tid >> 6;   // 4 waves

    if (tid < G_NUMS) { s_qt[tid] = qtau[bg0 + tid]; s_cnt[tid] = 0; }
    // stage tile into SoA: scalar coalesced reads, deinterleave on write
#pragma unroll
    for (int r = 0; r < (CHUNK * 3) / FTPB; r++) {   // 24 iters
        int j = r * FTPB + tid;
        float v = Pc[j];
        int p = j / 3, c = j - 3 * p;
        if (c == 0) s_x[p] = v; else if (c == 1) s_y[p] = v; else s_z[p] = v;
    }
    __syncthreads();

    // 8 points per thread, lane-stride-1 LDS reads (conflict-free), hoisted
    float x[8], y[8], z[8];
#pragma unroll
    for (int k = 0; k < 8; k++) {
        int p = tid + k * FTPB;
        x[k] = s_x[p]; y[k] = s_y[p]; z[k] = s_z[p];
    }
    for (int g = 0; g < G_NUMS; ++g) {
        float4 qt = s_qt[g];
        const unsigned taub = __float_as_uint(qt.w);
#pragma unroll
        for (int k = 0; k < 8; k++) {
            unsigned u = __float_as_uint(dist2f(x[k], y[k], z[k], qt.x, qt.y, qt.z));
            if (u < taub) {
                int p = atomicAdd(&s_cnt[g], 1);
                if (p < CAPB)
                    s_buf[g][p] = make_uint2(u, (unsigned)(base + tid + k * FTPB));
                else {                           // overflow fallback (rare)
                    int gp = atomicAdd(&counts[bg0 + g], 1);
                    if (gp < CAP)
                        surv[(size_t)(bg0 + g) * CAP + gp] =
                            make_uint2(u, (unsigned)(base + tid + k * FTPB));
                }
            }
        }
    }
    __syncthreads();                              // ALL buffer writes done (r7 race fix)

    for (int g = wid; g < G_NUMS; g += 4) {
        int n = s_cnt[g]; if (n > CAPB) n = CAPB;
        int bb = 0;
        if (lane == 0 && n > 0) bb = atomicAdd(&counts[bg0 + g], n);
        bb = __shfl(bb, 0);
        if (lane < n) {
            int pos = bb + lane;
            if (pos < CAP) surv[(size_t)(bg0 + g) * CAP + pos] = s_buf[g][lane];
        }
    }
}

// ---- 3x3 symmetric eigensolve (Jacobi, double) ----
__device__ void eig3(const float cf[6], double lam_out[3], double dir_out[3]) {
    double a[3][3], v[3][3];
    a[0][0] = cf[0]; a[0][1] = cf[1]; a[0][2] = cf[2];
    a[1][0] = cf[1]; a[1][1] = cf[3]; a[1][2] = cf[4];
    a[2][0] = cf[2]; a[2][1] = cf[4]; a[2][2] = cf[5];
    for (int i = 0; i < 3; i++)
        for (int j = 0; j < 3; j++) v[i][j] = (i == j) ? 1.0 : 0.0;
    for (int sweep = 0; sweep < 12; sweep++) {
        double off = a[0][1] * a[0][1] + a[0][2] * a[0][2] + a[1][2] * a[1][2];
        if (off == 0.0) break;
        for (int p = 0; p < 2; p++) {
            for (int q = p + 1; q < 3; q++) {
                double apq = a[p][q];
                if (apq == 0.0) continue;
                double app = a[p][p], aqq = a[q][q];
                double theta = (aqq - app) / (2.0 * apq);
                double t = (theta >= 0.0 ? 1.0 : -1.0) /
                           (fabs(theta) + sqrt(theta * theta + 1.0));
                double c = 1.0 / sqrt(t * t + 1.0);
                double s = t * c;
                a[p][p] = app - t * apq;
                a[q][q] = aqq + t * apq;
                a[p][q] = 0.0; a[q][p] = 0.0;
                for (int r = 0; r < 3; r++) {
                    if (r == p || r == q) continue;
                    double arp = a[r][p], arq = a[r][q];
                    a[r][p] = c * arp - s * arq; a[p][r] = a[r][p];
                    a[r][q] = s * arp + c * arq; a[q][r] = a[r][q];
                }
                for (int r = 0; r < 3; r++) {
                    double vrp = v[r][p], vrq = v[r][q];
                    v[r][p] = c * vrp - s * vrq;
                    v[r][q] = s * vrp + c * vrq;
                }
            }
        }
    }
    double l0 = a[0][0], l1 = a[1][1], l2 = a[2][2];
    int i0 = 0, i1 = 1, i2 = 2;
    if (l0 > l1) { double t = l0; l0 = l1; l1 = t; int ti = i0; i0 = i1; i1 = ti; }
    if (l1 > l2) { double t = l1; l1 = l2; l2 = t; int ti = i1; i1 = i2; i2 = ti; }
    if (l0 > l1) { double t = l0; l0 = l1; l1 = t; int ti = i0; i0 = i1; i1 = ti; }
    lam_out[0] = l0; lam_out[1] = l1; lam_out[2] = l2;
    dir_out[0] = v[0][i2]; dir_out[1] = v[1][i2]; dir_out[2] = v[2][i2];
}

// Exact top-100 among survivors. PHASE 0: mean + tau1. PHASE 1: covariance +
// tail-block finalize (r6-proven handshake, absmax 0.0).
template <int PHASE>
__global__ __launch_bounds__(TPB)
void select_kernel(const float* __restrict__ pts,
                   const float4* __restrict__ qtau_cur,
                   float4* __restrict__ qtau_next,
                   const uint2* __restrict__ surv, int* __restrict__ counts,
                   float* __restrict__ gmeans, float* __restrict__ covs,
                   float* __restrict__ out) {
    __shared__ unsigned s_hist[BINS];
    __shared__ unsigned s_wsum[NWAVES];
    __shared__ unsigned s_T;
    __shared__ int s_nd, s_nt;
    __shared__ int s_sel[G_SIZE];
    __shared__ unsigned s_tu[TIE_CAP];
    __shared__ int s_ti[TIE_CAP];
    __shared__ float s_acc[3], s_cov[6];
    __shared__ int s_last;
    __shared__ float s_dir[NG_TOT][3];
    __shared__ float s_gm[NG_TOT][3];
    __shared__ float s_pe[NWAVES], s_ps[NWAVES];

    const int blk = blockIdx.x;
    const int b = blk % NB, g = blk / NB;
    const int gi = b * G_NUMS + g;
    const float* __restrict__ P = pts + (size_t)b * (N_PTS * 3);
    const int tid = threadIdx.x, lane = tid & 63, wid = tid >> 6;

    const float4 qt = qtau_cur[gi];
    const unsigned tau = __float_as_uint(qt.w);
    int S = counts[gi]; if (S > CAP) S = CAP;
    const uint2* __restrict__ sv = surv + (size_t)gi * CAP;

    for (int j = tid; j < BINS; j += TPB) s_hist[j] = 0u;
    if (tid == 0) { s_T = 0u; s_nd = 0; s_nt = 0; }
    if (tid < 3) s_acc[tid] = 0.f;
    if (tid < 6) s_cov[tid] = 0.f;
    __syncthreads();

    unsigned hb = 32u - (unsigned)__clz(tau - 1u);
    unsigned sh = hb > 12u ? hb - 12u : 0u;
    for (int i = tid; i < S; i += TPB) atomicAdd(&s_hist[sv[i].x >> sh], 1u);
    __syncthreads();
    unsigned T2 = find_bin(s_hist, s_wsum, &s_T, G_SIZE, tid, lane, wid);
    const unsigned lo = T2 << sh;

    for (int i = tid; i < S; i += TPB) {
        unsigned u = sv[i].x;
        if (u < lo) {
            int p = atomicAdd(&s_nd, 1);
            if (p < G_SIZE) s_sel[p] = (int)sv[i].y;
        } else if ((u >> sh) == T2) {
            int p = atomicAdd(&s_nt, 1);
            if (p < TIE_CAP) { s_tu[p] = u; s_ti[p] = (int)sv[i].y; }
        }
    }
    __syncthreads();
    if (tid == 0) {
        int nd = s_nd; if (nd > G_SIZE) nd = G_SIZE;
        int need = G_SIZE - nd;
        int ec = s_nt; if (ec > TIE_CAP) ec = TIE_CAP;
        for (int a = 0; a < need && a < ec; ++a) {
            int best = a;
            for (int j = a + 1; j < ec; ++j)
                if (s_tu[j] < s_tu[best] ||
                    (s_tu[j] == s_tu[best] && s_ti[j] < s_ti[best])) best = j;
            unsigned tu = s_tu[best]; s_tu[best] = s_tu[a]; s_tu[a] = tu;
            int ti = s_ti[best]; s_ti[best] = s_ti[a]; s_ti[a] = ti;
            s_sel[nd + a] = s_ti[a];
        }
    }
    __syncthreads();

    float px = 0.f, py = 0.f, pz = 0.f;
    if (tid < G_SIZE) {
        const float* pp = P + 3 * (size_t)s_sel[tid];
        px = pp[0]; py = pp[1]; pz = pp[2];
        atomicAdd(&s_acc[0], px);
        atomicAdd(&s_acc[1], py);
        atomicAdd(&s_acc[2], pz);
    }
    __syncthreads();
    const float mx = s_acc[0] * (1.0f / G_SIZE);
    const float my = s_acc[1] * (1.0f / G_SIZE);
    const float mz = s_acc[2] * (1.0f / G_SIZE);

    if (PHASE == 0) {
        if (tid < 3) gmeans[gi * 3 + tid] = (tid == 0 ? mx : tid == 1 ? my : mz);
        unsigned tau1 = sample_tau((const float4*)P, mx, my, mz,
                                   s_hist, s_wsum, &s_T, tid, lane, wid);
        if (tid == 0)
            qtau_next[gi] = make_float4(mx, my, mz, __uint_as_float(tau1));
    } else {
        if (tid < G_SIZE) {
            float x = px - mx, y = py - my, z = pz - mz;
            atomicAdd(&s_cov[0], x * x);
            atomicAdd(&s_cov[1], x * y);
            atomicAdd(&s_cov[2], x * z);
            atomicAdd(&s_cov[3], y * y);
            atomicAdd(&s_cov[4], y * z);
            atomicAdd(&s_cov[5], z * z);
        }
        __syncthreads();
        if (tid < 6) covs[gi * 6 + tid] = s_cov[tid] * (1.0f / G_SIZE);

        // ---- tail-block handshake (verbatim r6 pattern, absmax 0.0) ----
        __syncthreads();
        if (tid == 0) {
            __threadfence();
            int old = __hip_atomic_fetch_add(&counts[DONE_IDX], 1,
                                             __ATOMIC_ACQ_REL,
                                             __HIP_MEMORY_SCOPE_AGENT);
            s_last = (old == NG_TOT - 1) ? 1 : 0;
        }
        __syncthreads();
        if (!s_last) return;
        __threadfence();

        float et = 0.f;
        if (tid < NG_TOT) {
            float cf[6];
#pragma unroll
            for (int j = 0; j < 6; j++)
                cf[j] = __hip_atomic_load(&covs[tid * 6 + j], __ATOMIC_RELAXED,
                                          __HIP_MEMORY_SCOPE_AGENT);
            double lam[3], dir[3];
            eig3(cf, lam, dir);
            double denom = lam[0] + lam[1] + lam[2] + 1e-9;
            et = (float)((lam[2] - lam[1]) / denom);
            s_dir[tid][0] = (float)dir[0];
            s_dir[tid][1] = (float)dir[1];
            s_dir[tid][2] = (float)dir[2];
            s_gm[tid][0] = gmeans[tid * 3 + 0];   // prev dispatch: plain load ok
            s_gm[tid][1] = gmeans[tid * 3 + 1];
            s_gm[tid][2] = gmeans[tid * 3 + 2];
        }
        __syncthreads();
        float st = 0.f;
        if (tid < NG_TOT) {
            int bb = tid / G_NUMS, g0 = tid % G_NUMS;
            float gx = s_gm[tid][0], gy = s_gm[tid][1], gz = s_gm[tid][2];
            float bd = 3.4e38f; int bj = 0;
            for (int gg = 0; gg < G_NUMS; gg++) {
                if (gg == g0) continue;
                int o = bb * G_NUMS + gg;
                float dx = gx - s_gm[o][0];
                float dy = gy - s_gm[o][1];
                float dz = gz - s_gm[o][2];
                float d = dx * dx + dy * dy + dz * dz;
                if (d < bd) { bd = d; bj = gg; }
            }
            int o = bb * G_NUMS + bj;
            float cosv = s_dir[tid][0] * s_dir[o][0] +
                         s_dir[tid][1] * s_dir[o][1] +
                         s_dir[tid][2] * s_dir[o][2];
            st = 1.f - cosv * cosv;
        }
        float e = et, s2 = st;
#pragma unroll
        for (int off = 32; off > 0; off >>= 1) {
            e += __shfl_down(e, off);
            s2 += __shfl_down(s2, off);
        }
        if (lane == 0) { s_pe[wid] = e; s_ps[wid] = s2; }
        __syncthreads();
        if (tid == 0) {
            float se = 0.f, ss = 0.f;
            for (int w = 0; w < NWAVES; w++) { se += s_pe[w]; ss += s_ps[w]; }
            out[0] = -se / (float)NB + ss / (float)NG_TOT;
        }
    }
}

extern "C" void kernel_launch(void* const* d_in, const int* in_sizes, int n_in,
                              void* d_out, int out_size, void* d_ws, size_t ws_size,
                              hipStream_t stream) {
    const float* pts = (const float*)d_in[0];
    float* out = (float*)d_out;

    float4* qtau0 = (float4*)d_ws;                  // 240
    float4* qtau1 = qtau0 + NG_TOT;                 // 240
    float* gmeans = (float*)(qtau1 + NG_TOT);       // 240*3
    float* covs = gmeans + NG_TOT * 3;              // 240*6
    int* count0 = (int*)(covs + NG_TOT * 6);        // 256
    int* count1 = count0 + 256;                     // 256 (incl. done counter)
    uint2* surv0 = (uint2*)(count1 + 256);          // 240*CAP
    uint2* surv1 = surv0 + (size_t)NG_TOT * CAP;    // 240*CAP  (~4.9 MB total)

    tau0_kernel<<<NG_TOT, TPB, 0, stream>>>(pts, qtau0, count0, count1);
    filter_kernel<<<NB * NCHUNK, FTPB, 0, stream>>>(pts, qtau0, count0, surv0);
    select_kernel<0><<<NG_TOT, TPB, 0, stream>>>(pts, qtau0, qtau1, surv0, count0,
                                                 gmeans, covs, out);
    filter_kernel<<<NB * NCHUNK, FTPB, 0, stream>>>(pts, qtau1, count1, surv1);
    select_kernel<1><<<NG_TOT, TPB, 0, stream>>>(pts, qtau1, nullptr, surv1, count1,
                                                 gmeans, covs, out);
}